// Round 3
// baseline (363.268 us; speedup 1.0000x reference)
//
#include <hip/hip_runtime.h>
#include <hip/hip_fp16.h>

#define D_FEAT 128
#define THRESH 0.01f
#define EPS_F  1e-8f

#define NPB 64          // nodes per block in pass A
#define ROWF 132        // padded row stride in floats (128 + 16B pad)

#define NBUCK 2048      // (srcSlice 3b) << 8 | (dstBlk 8b)

typedef _Float16 half2_t __attribute__((ext_vector_type(2)));

// ---------------------------------------------------------------------------
// Exact helpers: bit-exact replication of numpy's fp32 pipeline
// (8-accumulator pairwise sum). Proven absmax=0 in prior rounds.
// ---------------------------------------------------------------------------

__device__ float edge_out_scalar(const float* __restrict__ feat,
                                 float w, int s, int d) {
#pragma clang fp contract(off)
    const float* fs = feat + (size_t)s * D_FEAT;
    const float* fd = feat + (size_t)d * D_FEAT;
    float r[8], rs[8], rd[8];
#pragma unroll
    for (int j = 0; j < 8; ++j) {
        float a = fs[j], b = fd[j];
        r[j]  = a * b;
        rs[j] = a * a;
        rd[j] = b * b;
    }
    for (int k = 1; k < 16; ++k) {
#pragma unroll
        for (int j = 0; j < 8; ++j) {
            float a = fs[8 * k + j], b = fd[8 * k + j];
            r[j]  = r[j]  + a * b;
            rs[j] = rs[j] + a * a;
            rd[j] = rd[j] + b * b;
        }
    }
    float inner = ((r[0]  + r[1])  + (r[2]  + r[3]))  + ((r[4]  + r[5])  + (r[6]  + r[7]));
    float ss    = ((rs[0] + rs[1]) + (rs[2] + rs[3])) + ((rs[4] + rs[5]) + (rs[6] + rs[7]));
    float dd    = ((rd[0] + rd[1]) + (rd[2] + rd[3])) + ((rd[4] + rd[5]) + (rd[6] + rd[7]));
    float ns = __fsqrt_rn(ss);
    float nd = __fsqrt_rn(dd);
    float denom = ns * nd + EPS_F;
    float sim = inner / denom;
    float keep = (sim >= THRESH) ? 1.0f : 0.0f;
    float diag = (s == d) ? 2.0f : 1.0f;
    return (w * keep) * diag;
}

__device__ __forceinline__ float exact_sim_pairlanes(const float* __restrict__ feat,
                                                     int src, int dst, int h) {
#pragma clang fp contract(off)
    const float4* fs = (const float4*)(feat + (size_t)src * D_FEAT);
    const float4* fd = (const float4*)(feat + (size_t)dst * D_FEAT);
    float r[4], rs[4], rd[4];
    {
        float4 a = fs[h];
        float4 b = fd[h];
        r[0]  = a.x * b.x; r[1]  = a.y * b.y; r[2]  = a.z * b.z; r[3]  = a.w * b.w;
        rs[0] = a.x * a.x; rs[1] = a.y * a.y; rs[2] = a.z * a.z; rs[3] = a.w * a.w;
        rd[0] = b.x * b.x; rd[1] = b.y * b.y; rd[2] = b.z * b.z; rd[3] = b.w * b.w;
    }
#pragma unroll
    for (int k = 1; k < 16; ++k) {
        float4 a = fs[2 * k + h];
        float4 b = fd[2 * k + h];
        r[0]  = r[0]  + a.x * b.x;  r[1]  = r[1]  + a.y * b.y;
        r[2]  = r[2]  + a.z * b.z;  r[3]  = r[3]  + a.w * b.w;
        rs[0] = rs[0] + a.x * a.x;  rs[1] = rs[1] + a.y * a.y;
        rs[2] = rs[2] + a.z * a.z;  rs[3] = rs[3] + a.w * a.w;
        rd[0] = rd[0] + b.x * b.x;  rd[1] = rd[1] + b.y * b.y;
        rd[2] = rd[2] + b.z * b.z;  rd[3] = rd[3] + b.w * b.w;
    }
    float A  = (r[0]  + r[1])  + (r[2]  + r[3]);
    float As = (rs[0] + rs[1]) + (rs[2] + rs[3]);
    float Ad = (rd[0] + rd[1]) + (rd[2] + rd[3]);

    float inner = A  + __shfl_xor(A, 1, 64);
    float ssE   = As + __shfl_xor(As, 1, 64);
    float ddE   = Ad + __shfl_xor(Ad, 1, 64);

    float ns    = __fsqrt_rn(ssE);
    float nd    = __fsqrt_rn(ddE);
    float den   = ns * nd + EPS_F;
    return inner / den;
}

__device__ __forceinline__ float exact_inner_pairlanes(const float* __restrict__ feat,
                                                       int src, int dst, int h) {
#pragma clang fp contract(off)
    const float4* fs = (const float4*)(feat + (size_t)src * D_FEAT);
    const float4* fd = (const float4*)(feat + (size_t)dst * D_FEAT);
    float r[4];
    {
        float4 a = fs[h];
        float4 b = fd[h];
        r[0] = a.x * b.x; r[1] = a.y * b.y; r[2] = a.z * b.z; r[3] = a.w * b.w;
    }
#pragma unroll
    for (int k = 1; k < 16; ++k) {
        float4 a = fs[2 * k + h];
        float4 b = fd[2 * k + h];
        r[0] = r[0] + a.x * b.x;  r[1] = r[1] + a.y * b.y;
        r[2] = r[2] + a.z * b.z;  r[3] = r[3] + a.w * b.w;
    }
    float A = (r[0] + r[1]) + (r[2] + r[3]);
    return A + __shfl_xor(A, 1, 64);
}

// ---------------------------------------------------------------------------
// Fallback kernel (ws too small / odd feature count): round-1 proven path.
// ---------------------------------------------------------------------------
__global__ __launch_bounds__(256) void jaccard_edge_kernel(
    const int* __restrict__ ei, const float* __restrict__ w,
    const float* __restrict__ feat, float* __restrict__ out,
    int P, int E)
{
    int t    = blockIdx.x * blockDim.x + threadIdx.x;
    int pair = t >> 1;
    int half = t & 1;
    if (pair >= P) return;

    int src = ei[pair];
    int dst = ei[E + pair];

    float sim  = exact_sim_pairlanes(feat, src, dst, half);
    float keep = (sim >= THRESH) ? 1.0f : 0.0f;

    if (half == 0) {
        float diag = (src == dst) ? 2.0f : 1.0f;
        out[pair] = (w[pair] * keep) * diag;
        int m = P + pair;
        if (m < E) {
            int s2 = ei[m];
            int d2 = ei[E + m];
            if (s2 == dst && d2 == src) out[m] = (w[m] * keep) * diag;
            else                        out[m] = edge_out_scalar(feat, w[m], s2, d2);
        }
    }
}

// ---------------------------------------------------------------------------
// Pass A v3: LDS-staged (unchanged, proven exact). See prior rounds.
// ---------------------------------------------------------------------------
__global__ __launch_bounds__(256) void norm_convert_kernel(
    const float* __restrict__ feat, __half* __restrict__ hfeat,
    float* __restrict__ nrm, int nNodes)
{
#pragma clang fp contract(off)
    __shared__ float lds[NPB * ROWF];
    __shared__ float lr[NPB];

    int block0 = blockIdx.x * NPB;
    int nvalid = nNodes - block0; if (nvalid > NPB) nvalid = NPB;
    int tid = threadIdx.x;

    const float4* gsrc = (const float4*)(feat + (size_t)block0 * D_FEAT);
    float4* lds4 = (float4*)lds;
    int nf4 = nvalid * (D_FEAT / 4);
    for (int i = tid; i < nf4; i += 256) {
        int n = i >> 5, c = i & 31;
        lds4[n * (ROWF / 4) + c] = gsrc[i];
    }
    __syncthreads();

    int ln = tid >> 2, q = tid & 3;
    if (ln < nvalid) {
        const float2* lrow = (const float2*)(lds + ln * ROWF);
        float2 a = lrow[q];
        float r0 = a.x * a.x, r1 = a.y * a.y;
#pragma unroll
        for (int k = 1; k < 16; ++k) {
            float2 v = lrow[4 * k + q];
            r0 = r0 + v.x * v.x;
            r1 = r1 + v.y * v.y;
        }
        float s  = r0 + r1;
        float ss = s + __shfl_xor(s, 1, 64);
        ss       = ss + __shfl_xor(ss, 2, 64);
        float na = __fsqrt_rn(ss);
        if (q == 0) {
            nrm[block0 + ln] = na;
            bool ok = isfinite(na) && (na >= 0.03f);
            lr[ln] = ok ? (1.0f / na) : __builtin_nanf("");
        }
    }
    __syncthreads();

    uint4* gdst = (uint4*)(hfeat + (size_t)block0 * D_FEAT);
    int nu4 = nvalid * (D_FEAT / 8);
    for (int i = tid; i < nu4; i += 256) {
        int n = i >> 4, c = i & 15;
        float r = lr[n];
        const float4* lp = (const float4*)(lds + n * ROWF + 8 * c);
        float4 x = lp[0], y = lp[1];
        __half2 h0 = __floats2half2_rn(x.x * r, x.y * r);
        __half2 h1 = __floats2half2_rn(x.z * r, x.w * r);
        __half2 h2 = __floats2half2_rn(y.x * r, y.y * r);
        __half2 h3 = __floats2half2_rn(y.z * r, y.w * r);
        uint4 o;
        o.x = __builtin_bit_cast(unsigned, h0);
        o.y = __builtin_bit_cast(unsigned, h1);
        o.z = __builtin_bit_cast(unsigned, h2);
        o.w = __builtin_bit_cast(unsigned, h3);
        gdst[i] = o;
    }
}

// ---------------------------------------------------------------------------
// fdot2 helper
// ---------------------------------------------------------------------------
__device__ __forceinline__ float dot8_f16(uint4 ua, uint4 ub, float acc) {
    acc = __builtin_amdgcn_fdot2(__builtin_bit_cast(half2_t, ua.x),
                                 __builtin_bit_cast(half2_t, ub.x), acc, false);
    acc = __builtin_amdgcn_fdot2(__builtin_bit_cast(half2_t, ua.y),
                                 __builtin_bit_cast(half2_t, ub.y), acc, false);
    acc = __builtin_amdgcn_fdot2(__builtin_bit_cast(half2_t, ua.z),
                                 __builtin_bit_cast(half2_t, ub.z), acc, false);
    acc = __builtin_amdgcn_fdot2(__builtin_bit_cast(half2_t, ua.w),
                                 __builtin_bit_cast(half2_t, ub.w), acc, false);
    return acc;
}

// ---------------------------------------------------------------------------
// Pass B v1 (mid-tier fallback when ws fits hfeat+nrm but not the bins).
// Proven 56 µs in round 1.
// ---------------------------------------------------------------------------
__global__ __launch_bounds__(256) void jaccard_edge_f16u_kernel(
    const int* __restrict__ ei, const float* __restrict__ w,
    const float* __restrict__ feat, const __half* __restrict__ hfeat,
    const float* __restrict__ nrm, float* __restrict__ out, int P, int E)
{
#pragma clang fp contract(off)
    int t    = blockIdx.x * blockDim.x + threadIdx.x;
    int pair = t >> 2;
    int q    = t & 3;
    if (pair >= P) return;

    int src = __builtin_nontemporal_load(ei + pair);
    int dst = __builtin_nontemporal_load(ei + E + pair);

    float wp  = __builtin_nontemporal_load(w + pair);
    int   m   = P + pair;
    bool  hasm = (m < E);
    int s2 = 0, d2 = 0;
    float wm = 0.f;
    if (hasm) {
        s2 = __builtin_nontemporal_load(ei + m);
        d2 = __builtin_nontemporal_load(ei + E + m);
        wm = __builtin_nontemporal_load(w + m);
    }

    const uint4* ha = (const uint4*)(hfeat + (size_t)src * D_FEAT);
    const uint4* hb = (const uint4*)(hfeat + (size_t)dst * D_FEAT);

    uint4 A[4], B[4];
#pragma unroll
    for (int k = 0; k < 4; ++k) {
        A[k] = ha[4 * k + q];
        B[k] = hb[4 * k + q];
    }

    float d = 0.f;
#pragma unroll
    for (int k = 0; k < 4; ++k) d = dot8_f16(A[k], B[k], d);

    d += __shfl_xor(d, 1, 64);
    float dot = d + __shfl_xor(d, 2, 64);

    float diff = dot - THRESH;
    const float bnd = 1.2e-3f;

    float keep;
    if (fabsf(diff) > bnd && fabsf(dot) < 2.0f) {
        keep = (diff >= 0.f) ? 1.0f : 0.0f;
    } else {
        float se = 0.f;
        if (q < 2) {
            float inner = exact_inner_pairlanes(feat, src, dst, q);
            float den   = nrm[src] * nrm[dst] + EPS_F;
            se = inner / den;
        }
        keep = (se >= THRESH) ? 1.0f : 0.0f;
    }

    if (q == 0) {
        float diag = (src == dst) ? 2.0f : 1.0f;
        __builtin_nontemporal_store((wp * keep) * diag, out + pair);
        if (hasm) {
            if (s2 == dst && d2 == src) {
                __builtin_nontemporal_store((wm * keep) * diag, out + m);
            } else {
                out[m] = edge_out_scalar(feat, wm, s2, d2);
            }
        }
    }
}

// ---------------------------------------------------------------------------
// Binning preprocess: counting sort of pairs by (srcSlice<<8 | dstBlk).
// srcSlice aligns with XCD (blockIdx%8 idiom); dstBlk groups repeat-dst
// touches in time so they hit L2. Record order never affects FP values
// (one independent write per output slot) -> exactness preserved.
// ---------------------------------------------------------------------------
__device__ __forceinline__ int bucket_key(int a, int b, int nN) {
    int s   = (int)(((long long)a * 8)   / nN); if (s > 7)     s = 7;     if (s < 0)   s = 0;
    int blk = (int)(((long long)b * 256) / nN); if (blk > 255) blk = 255; if (blk < 0) blk = 0;
    return (s << 8) | blk;
}

__global__ __launch_bounds__(256) void bin_clear_kernel(int* __restrict__ cnt) {
    int t = threadIdx.x;
    for (int i = t; i < NBUCK; i += 256) cnt[i] = 0;
}

__global__ __launch_bounds__(256) void bin_hist_kernel(
    const int* __restrict__ ei, int* __restrict__ cnt,
    int P, int E, int nN)
{
    int stride = gridDim.x * blockDim.x;
    for (int p = blockIdx.x * blockDim.x + threadIdx.x; p < P; p += stride) {
        int src = ei[p];
        int dst = ei[E + p];
        atomicAdd(cnt + bucket_key(src, dst, nN), 1);
        int m = P + p;
        if (m < E) {
            int s2 = ei[m];
            int d2 = ei[E + m];
            if (!(s2 == dst && d2 == src))
                atomicAdd(cnt + bucket_key(s2, d2, nN), 1);
        }
    }
}

// 1 block, 256 threads: exclusive scan of 2048 counts -> cursor; meta[0..7]
// = sliceStart, meta[8..15] = sliceEnd.
__global__ __launch_bounds__(256) void bin_scan_kernel(
    const int* __restrict__ cnt, int* __restrict__ cursor, int* __restrict__ meta)
{
    __shared__ int part[256];
    int tid = threadIdx.x;
    int c[8];
    int sum = 0;
#pragma unroll
    for (int i = 0; i < 8; ++i) { c[i] = cnt[8 * tid + i]; sum += c[i]; }
    part[tid] = sum;
    __syncthreads();
    for (int off = 1; off < 256; off <<= 1) {
        int v = (tid >= off) ? part[tid - off] : 0;
        __syncthreads();
        part[tid] += v;
        __syncthreads();
    }
    int excl = part[tid] - sum;
    int run = excl;
#pragma unroll
    for (int i = 0; i < 8; ++i) { cursor[8 * tid + i] = run; run += c[i]; }
    if ((tid & 31) == 0) {
        int s = tid >> 5;
        meta[s] = excl;                     // sliceStart[s] (bucket s*256)
        if (s > 0) meta[8 + s - 1] = excl;  // sliceEnd[s-1]
    }
    if (tid == 255) meta[8 + 7] = part[255];  // total
}

__global__ __launch_bounds__(256) void bin_scatter_kernel(
    const int* __restrict__ ei, const float* __restrict__ w,
    int* __restrict__ cursor,
    int* __restrict__ rsrc, int* __restrict__ rdst,
    float* __restrict__ rwp, float* __restrict__ rwm,
    unsigned* __restrict__ ridx,
    int P, int E, int nN)
{
    int stride = gridDim.x * blockDim.x;
    for (int p = blockIdx.x * blockDim.x + threadIdx.x; p < P; p += stride) {
        int src = ei[p];
        int dst = ei[E + p];
        float wp = w[p];
        int m = P + p;
        bool mm = false;
        int s2 = 0, d2 = 0;
        float wm = 0.f;
        if (m < E) {
            s2 = ei[m];
            d2 = ei[E + m];
            wm = w[m];
            mm = (s2 == dst && d2 == src);
        }
        int pos = atomicAdd(cursor + bucket_key(src, dst, nN), 1);
        rsrc[pos] = src;
        rdst[pos] = dst;
        rwp[pos]  = wp;
        rwm[pos]  = mm ? wm : 0.f;
        ridx[pos] = (unsigned)p | (mm ? 0x80000000u : 0u);
        if (m < E && !mm) {
            int pos2 = atomicAdd(cursor + bucket_key(s2, d2, nN), 1);
            rsrc[pos2] = s2;
            rdst[pos2] = d2;
            rwp[pos2]  = wm;
            rwm[pos2]  = 0.f;
            ridx[pos2] = (unsigned)m;       // standalone: no mirror bit
        }
    }
}

// ---------------------------------------------------------------------------
// Pass B v3: binned. Block bid serves slice bid%8 (XCD-aligned), grid-strides
// within its slice. Per-record math bit-identical to v1.
// ---------------------------------------------------------------------------
__global__ __launch_bounds__(256) void jaccard_binned_kernel(
    const int* __restrict__ rsrc, const int* __restrict__ rdst,
    const float* __restrict__ rwp, const float* __restrict__ rwm,
    const unsigned* __restrict__ ridx, const int* __restrict__ meta,
    const float* __restrict__ feat, const __half* __restrict__ hfeat,
    const float* __restrict__ nrm, float* __restrict__ out, int P)
{
#pragma clang fp contract(off)
    int slice = blockIdx.x & 7;
    int s0 = meta[slice];
    int s1 = meta[8 + slice];
    int quad = threadIdx.x >> 2;
    int q    = threadIdx.x & 3;
    int blocksPerSlice = gridDim.x >> 3;
    int bchunk = blockIdx.x >> 3;

    for (int start = s0 + bchunk * 64; start < s1; start += blocksPerSlice * 64) {
        int rec  = start + quad;
        bool act = (rec < s1);
        int recc = act ? rec : (s1 - 1);   // s1>start>=s0 => s1-1 valid

        int src      = rsrc[recc];
        int dst      = rdst[recc];
        float wp     = rwp[recc];
        float wm     = rwm[recc];
        unsigned ide = ridx[recc];

        const uint4* ha = (const uint4*)(hfeat + (size_t)src * D_FEAT);
        const uint4* hb = (const uint4*)(hfeat + (size_t)dst * D_FEAT);

        uint4 A[4], B[4];
#pragma unroll
        for (int k = 0; k < 4; ++k) {
            A[k] = ha[4 * k + q];
            B[k] = hb[4 * k + q];
        }

        float d = 0.f;
#pragma unroll
        for (int k = 0; k < 4; ++k) d = dot8_f16(A[k], B[k], d);

        d += __shfl_xor(d, 1, 64);
        float dot = d + __shfl_xor(d, 2, 64);

        float diff = dot - THRESH;
        const float bnd = 1.2e-3f;

        float keep;
        if (fabsf(diff) > bnd && fabsf(dot) < 2.0f) {   // quad-uniform
            keep = (diff >= 0.f) ? 1.0f : 0.0f;
        } else {
            float se = 0.f;
            if (q < 2) {
                float inner = exact_inner_pairlanes(feat, src, dst, q);
                float den   = nrm[src] * nrm[dst] + EPS_F;
                se = inner / den;
            }
            keep = (se >= THRESH) ? 1.0f : 0.0f;   // valid on q==0 (writer)
        }

        if (act && q == 0) {
            int idx = (int)(ide & 0x7fffffffu);
            float diag = (src == dst) ? 2.0f : 1.0f;
            out[idx] = (wp * keep) * diag;
            if (ide & 0x80000000u) out[idx + P] = (wm * keep) * diag;
        }
    }
}

extern "C" void kernel_launch(void* const* d_in, const int* in_sizes, int n_in,
                              void* d_out, int out_size, void* d_ws, size_t ws_size,
                              hipStream_t stream) {
    const int*   ei   = (const int*)d_in[0];     // [2, E] flattened (int32)
    const float* w    = (const float*)d_in[1];   // [E]
    const float* feat = (const float*)d_in[2];   // [N, 128]
    float*       out  = (float*)d_out;           // [E]

    int E = in_sizes[1];
    int P = E - E / 2;                 // ceil(E/2)
    long nfeat = in_sizes[2];
    long nNodes = nfeat / D_FEAT;

    size_t hbytes  = (size_t)nfeat * sizeof(__half);
    size_t need1   = hbytes + (size_t)nNodes * sizeof(float);

    if (P <= 0) return;

    if (ws_size < need1 || (nfeat % D_FEAT) != 0) {
        int threads = 2 * P;
        int grid = (threads + 255) / 256;
        jaccard_edge_kernel<<<grid, 256, 0, stream>>>(ei, w, feat, out, P, E);
        return;
    }

    // ws layout
    size_t o = 0;
    __half* hfeat = (__half*)((char*)d_ws + o);  o += hbytes;
    o = (o + 255) & ~(size_t)255;
    float* nrm = (float*)((char*)d_ws + o);      o += (size_t)nNodes * sizeof(float);
    o = (o + 255) & ~(size_t)255;
    size_t orec = o;
    int*      rsrc = (int*)((char*)d_ws + o);       o += (size_t)E * 4;
    int*      rdst = (int*)((char*)d_ws + o);       o += (size_t)E * 4;
    float*    rwp  = (float*)((char*)d_ws + o);     o += (size_t)E * 4;
    float*    rwm  = (float*)((char*)d_ws + o);     o += (size_t)E * 4;
    unsigned* ridx = (unsigned*)((char*)d_ws + o);  o += (size_t)E * 4;
    int* cnt    = (int*)((char*)d_ws + o);          o += NBUCK * 4;
    int* cursor = (int*)((char*)d_ws + o);          o += NBUCK * 4;
    int* meta   = (int*)((char*)d_ws + o);          o += 32 * 4;
    size_t need2 = o;

    int gridA = (int)((nNodes + NPB - 1) / NPB);
    norm_convert_kernel<<<gridA, 256, 0, stream>>>(feat, hfeat, nrm, (int)nNodes);

    if (ws_size < need2 || nNodes < 8) {
        // mid-tier: proven unbinned pass B
        int tB = 4 * P;
        jaccard_edge_f16u_kernel<<<(tB + 255) / 256, 256, 0, stream>>>(
            ei, w, feat, hfeat, nrm, out, P, E);
        return;
    }

    int gridH = (P + 255) / 256; if (gridH > 2048) gridH = 2048;
    bin_clear_kernel<<<1, 256, 0, stream>>>(cnt);
    bin_hist_kernel<<<gridH, 256, 0, stream>>>(ei, cnt, P, E, (int)nNodes);
    bin_scan_kernel<<<1, 256, 0, stream>>>(cnt, cursor, meta);
    bin_scatter_kernel<<<gridH, 256, 0, stream>>>(ei, w, cursor,
                                                  rsrc, rdst, rwp, rwm, ridx,
                                                  P, E, (int)nNodes);

    // binned pass B: 8-aligned grid, grid-stride within slice
    int bps = (P / 8 + 63) / 64 + 2;       // blocks per slice (estimate; stride covers skew)
    int gridB = 8 * bps;
    jaccard_binned_kernel<<<gridB, 256, 0, stream>>>(
        rsrc, rdst, rwp, rwm, ridx, meta, feat, hfeat, nrm, out, P);
    (void)orec;
}

// Round 4
// 154.384 us; speedup vs baseline: 2.3530x; 2.3530x over previous
//
#include <hip/hip_runtime.h>
#include <hip/hip_fp16.h>

#define D_FEAT 128
#define THRESH 0.01f
#define EPS_F  1e-8f

typedef _Float16 half2_t __attribute__((ext_vector_type(2)));

// ---------------------------------------------------------------------------
// Exact helpers: bit-exact replication of numpy's fp32 pipeline
// (8-accumulator pairwise sum). Proven absmax=0 in prior rounds.
// ---------------------------------------------------------------------------

__device__ float edge_out_scalar(const float* __restrict__ feat,
                                 float w, int s, int d) {
#pragma clang fp contract(off)
    const float* fs = feat + (size_t)s * D_FEAT;
    const float* fd = feat + (size_t)d * D_FEAT;
    float r[8], rs[8], rd[8];
#pragma unroll
    for (int j = 0; j < 8; ++j) {
        float a = fs[j], b = fd[j];
        r[j]  = a * b;
        rs[j] = a * a;
        rd[j] = b * b;
    }
    for (int k = 1; k < 16; ++k) {
#pragma unroll
        for (int j = 0; j < 8; ++j) {
            float a = fs[8 * k + j], b = fd[8 * k + j];
            r[j]  = r[j]  + a * b;
            rs[j] = rs[j] + a * a;
            rd[j] = rd[j] + b * b;
        }
    }
    float inner = ((r[0]  + r[1])  + (r[2]  + r[3]))  + ((r[4]  + r[5])  + (r[6]  + r[7]));
    float ss    = ((rs[0] + rs[1]) + (rs[2] + rs[3])) + ((rs[4] + rs[5]) + (rs[6] + rs[7]));
    float dd    = ((rd[0] + rd[1]) + (rd[2] + rd[3])) + ((rd[4] + rd[5]) + (rd[6] + rd[7]));
    float ns = __fsqrt_rn(ss);
    float nd = __fsqrt_rn(dd);
    float denom = ns * nd + EPS_F;
    float sim = inner / denom;
    float keep = (sim >= THRESH) ? 1.0f : 0.0f;
    float diag = (s == d) ? 2.0f : 1.0f;
    return (w * keep) * diag;
}

__device__ __forceinline__ float exact_sim_pairlanes(const float* __restrict__ feat,
                                                     int src, int dst, int h) {
#pragma clang fp contract(off)
    const float4* fs = (const float4*)(feat + (size_t)src * D_FEAT);
    const float4* fd = (const float4*)(feat + (size_t)dst * D_FEAT);
    float r[4], rs[4], rd[4];
    {
        float4 a = fs[h];
        float4 b = fd[h];
        r[0]  = a.x * b.x; r[1]  = a.y * b.y; r[2]  = a.z * b.z; r[3]  = a.w * b.w;
        rs[0] = a.x * a.x; rs[1] = a.y * a.y; rs[2] = a.z * a.z; rs[3] = a.w * a.w;
        rd[0] = b.x * b.x; rd[1] = b.y * b.y; rd[2] = b.z * b.z; rd[3] = b.w * b.w;
    }
#pragma unroll
    for (int k = 1; k < 16; ++k) {
        float4 a = fs[2 * k + h];
        float4 b = fd[2 * k + h];
        r[0]  = r[0]  + a.x * b.x;  r[1]  = r[1]  + a.y * b.y;
        r[2]  = r[2]  + a.z * b.z;  r[3]  = r[3]  + a.w * b.w;
        rs[0] = rs[0] + a.x * a.x;  rs[1] = rs[1] + a.y * a.y;
        rs[2] = rs[2] + a.z * a.z;  rs[3] = rs[3] + a.w * a.w;
        rd[0] = rd[0] + b.x * b.x;  rd[1] = rd[1] + b.y * b.y;
        rd[2] = rd[2] + b.z * b.z;  rd[3] = rd[3] + b.w * b.w;
    }
    float A  = (r[0]  + r[1])  + (r[2]  + r[3]);
    float As = (rs[0] + rs[1]) + (rs[2] + rs[3]);
    float Ad = (rd[0] + rd[1]) + (rd[2] + rd[3]);

    float inner = A  + __shfl_xor(A, 1, 64);
    float ssE   = As + __shfl_xor(As, 1, 64);
    float ddE   = Ad + __shfl_xor(Ad, 1, 64);

    float ns    = __fsqrt_rn(ssE);
    float nd    = __fsqrt_rn(ddE);
    float den   = ns * nd + EPS_F;
    return inner / den;
}

__device__ __forceinline__ float exact_inner_pairlanes(const float* __restrict__ feat,
                                                       int src, int dst, int h) {
#pragma clang fp contract(off)
    const float4* fs = (const float4*)(feat + (size_t)src * D_FEAT);
    const float4* fd = (const float4*)(feat + (size_t)dst * D_FEAT);
    float r[4];
    {
        float4 a = fs[h];
        float4 b = fd[h];
        r[0] = a.x * b.x; r[1] = a.y * b.y; r[2] = a.z * b.z; r[3] = a.w * b.w;
    }
#pragma unroll
    for (int k = 1; k < 16; ++k) {
        float4 a = fs[2 * k + h];
        float4 b = fd[2 * k + h];
        r[0] = r[0] + a.x * b.x;  r[1] = r[1] + a.y * b.y;
        r[2] = r[2] + a.z * b.z;  r[3] = r[3] + a.w * b.w;
    }
    float A = (r[0] + r[1]) + (r[2] + r[3]);
    return A + __shfl_xor(A, 1, 64);
}

// ---------------------------------------------------------------------------
// Fallback kernel (ws too small / odd feature count): round-1 proven path.
// ---------------------------------------------------------------------------
__global__ __launch_bounds__(256) void jaccard_edge_kernel(
    const int* __restrict__ ei, const float* __restrict__ w,
    const float* __restrict__ feat, float* __restrict__ out,
    int P, int E)
{
    int t    = blockIdx.x * blockDim.x + threadIdx.x;
    int pair = t >> 1;
    int half = t & 1;
    if (pair >= P) return;

    int src = ei[pair];
    int dst = ei[E + pair];

    float sim  = exact_sim_pairlanes(feat, src, dst, half);
    float keep = (sim >= THRESH) ? 1.0f : 0.0f;

    if (half == 0) {
        float diag = (src == dst) ? 2.0f : 1.0f;
        out[pair] = (w[pair] * keep) * diag;
        int m = P + pair;
        if (m < E) {
            int s2 = ei[m];
            int d2 = ei[E + m];
            if (s2 == dst && d2 == src) out[m] = (w[m] * keep) * diag;
            else                        out[m] = edge_out_scalar(feat, w[m], s2, d2);
        }
    }
}

// ---------------------------------------------------------------------------
// Pass A v4: NO LDS, NO barriers. One quad (4 lanes) per node, straight from
// global. Lane q retains its 16 exact float2 pieces (elements {8k+2q,8k+2q+1},
// float2 index 4k+q — identical mapping to the proven LDS phase 2) in
// registers. Accumulation order identical to proven version: r0,r1 over
// k=0..15 sequential, s=r0+r1, shfl_xor(1), shfl_xor(2) — bit-identical
// numpy pairwise tree. All 4 lanes compute na / 1/na redundantly
// (deterministic ops -> identical values; replaces the LDS lr[] broadcast).
// Conversion: same __floats2half2_rn(v*r) products -> identical fp16 bits.
// Bad rows (na<0.03 / non-finite) NaN-poisoned as before.
// Stores: each lane writes its 16 half2 pieces; each 128B line is fully
// written across the k-steps (fully dirty -> no RMW waste).
// Occupancy: ~48 VGPR, no LDS -> 8 waves/SIMD, pure streaming.
// ---------------------------------------------------------------------------
__global__ __launch_bounds__(256) void norm_convert_kernel(
    const float* __restrict__ feat, __half* __restrict__ hfeat,
    float* __restrict__ nrm, int nNodes)
{
#pragma clang fp contract(off)
    int tid  = blockIdx.x * blockDim.x + threadIdx.x;
    int lane = tid & 63;
    int n    = (tid >> 6) * 16 + (lane >> 2);   // wave covers 16 nodes
    int q    = lane & 3;
    if (n >= nNodes) return;    // quad-uniform exit (n shared by all 4 lanes)

    const float2* row = (const float2*)(feat + (size_t)n * D_FEAT);
    float2 v[16];
#pragma unroll
    for (int k = 0; k < 16; ++k) v[k] = row[4 * k + q];

    float r0 = v[0].x * v[0].x;
    float r1 = v[0].y * v[0].y;
#pragma unroll
    for (int k = 1; k < 16; ++k) {
        r0 = r0 + v[k].x * v[k].x;
        r1 = r1 + v[k].y * v[k].y;
    }
    float s  = r0 + r1;                     // r[2q] + r[2q+1]
    float ss = s + __shfl_xor(s, 1, 64);    // (s0+s1) | (s2+s3)
    ss       = ss + __shfl_xor(ss, 2, 64);  // full numpy tree (quad-local)
    float na = __fsqrt_rn(ss);

    bool ok  = isfinite(na) && (na >= 0.03f);
    float r  = ok ? (1.0f / na) : __builtin_nanf("");

    if (q == 0) nrm[n] = na;                // exact numpy node_norm

    __half* orow = hfeat + (size_t)n * D_FEAT;
#pragma unroll
    for (int k = 0; k < 16; ++k) {
        __half2 h = __floats2half2_rn(v[k].x * r, v[k].y * r);
        *(__half2*)(orow + 8 * k + 2 * q) = h;
    }
}

// ---------------------------------------------------------------------------
// fdot2 helper
// ---------------------------------------------------------------------------
__device__ __forceinline__ float dot8_f16(uint4 ua, uint4 ub, float acc) {
    acc = __builtin_amdgcn_fdot2(__builtin_bit_cast(half2_t, ua.x),
                                 __builtin_bit_cast(half2_t, ub.x), acc, false);
    acc = __builtin_amdgcn_fdot2(__builtin_bit_cast(half2_t, ua.y),
                                 __builtin_bit_cast(half2_t, ub.y), acc, false);
    acc = __builtin_amdgcn_fdot2(__builtin_bit_cast(half2_t, ua.z),
                                 __builtin_bit_cast(half2_t, ub.z), acc, false);
    acc = __builtin_amdgcn_fdot2(__builtin_bit_cast(half2_t, ua.w),
                                 __builtin_bit_cast(half2_t, ub.w), acc, false);
    return acc;
}

// ---------------------------------------------------------------------------
// Pass B v1 (proven 56 µs, round 1): quad layout, 4 lanes/pair. Screen =
// fdot2(u_hat, v_hat) vs CONSTANT rigorous bound 1.2e-3 (element rounding
// 9.79e-4 + fdot2 acc 7.9e-6 + numpy-side 1.2e-6 + subnormal 7.6e-6 + EPS
// shift 1.3e-7; na<0.03 rows NaN-poisoned). |dot|>=2 or NaN -> exact path.
// Borderline (~1.2%) -> exact fp32 numpy sim.
// ---------------------------------------------------------------------------
__global__ __launch_bounds__(256) void jaccard_edge_f16u_kernel(
    const int* __restrict__ ei, const float* __restrict__ w,
    const float* __restrict__ feat, const __half* __restrict__ hfeat,
    const float* __restrict__ nrm, float* __restrict__ out, int P, int E)
{
#pragma clang fp contract(off)
    int t    = blockIdx.x * blockDim.x + threadIdx.x;
    int pair = t >> 2;
    int q    = t & 3;
    if (pair >= P) return;

    int src = __builtin_nontemporal_load(ei + pair);
    int dst = __builtin_nontemporal_load(ei + E + pair);

    float wp  = __builtin_nontemporal_load(w + pair);
    int   m   = P + pair;
    bool  hasm = (m < E);
    int s2 = 0, d2 = 0;
    float wm = 0.f;
    if (hasm) {
        s2 = __builtin_nontemporal_load(ei + m);
        d2 = __builtin_nontemporal_load(ei + E + m);
        wm = __builtin_nontemporal_load(w + m);
    }

    const uint4* ha = (const uint4*)(hfeat + (size_t)src * D_FEAT);
    const uint4* hb = (const uint4*)(hfeat + (size_t)dst * D_FEAT);

    uint4 A[4], B[4];
#pragma unroll
    for (int k = 0; k < 4; ++k) {
        A[k] = ha[4 * k + q];
        B[k] = hb[4 * k + q];
    }

    float d = 0.f;
#pragma unroll
    for (int k = 0; k < 4; ++k) d = dot8_f16(A[k], B[k], d);

    // quad butterfly: bit-identical on all 4 lanes (IEEE a+b==b+a)
    d += __shfl_xor(d, 1, 64);
    float dot = d + __shfl_xor(d, 2, 64);

    float diff = dot - THRESH;
    const float bnd = 1.2e-3f;

    float keep;
    if (fabsf(diff) > bnd && fabsf(dot) < 2.0f) {   // quad-uniform decision
        keep = (diff >= 0.f) ? 1.0f : 0.0f;
    } else {
        // exact numpy sim: exact inner (fp32, numpy order) / exact denominator
        float se = 0.f;
        if (q < 2) {
            float inner = exact_inner_pairlanes(feat, src, dst, q);
            float den   = nrm[src] * nrm[dst] + EPS_F;   // mul then add
            se = inner / den;
        }
        keep = (se >= THRESH) ? 1.0f : 0.0f;   // valid on lane q==0 (writer)
    }

    if (q == 0) {
        float diag = (src == dst) ? 2.0f : 1.0f;
        __builtin_nontemporal_store((wp * keep) * diag, out + pair);
        if (hasm) {
            if (s2 == dst && d2 == src) {
                __builtin_nontemporal_store((wm * keep) * diag, out + m);
            } else {
                out[m] = edge_out_scalar(feat, wm, s2, d2);
            }
        }
    }
}

extern "C" void kernel_launch(void* const* d_in, const int* in_sizes, int n_in,
                              void* d_out, int out_size, void* d_ws, size_t ws_size,
                              hipStream_t stream) {
    const int*   ei   = (const int*)d_in[0];     // [2, E] flattened (int32)
    const float* w    = (const float*)d_in[1];   // [E]
    const float* feat = (const float*)d_in[2];   // [N, 128]
    float*       out  = (float*)d_out;           // [E]

    int E = in_sizes[1];
    int P = E - E / 2;                 // ceil(E/2)
    long nfeat = in_sizes[2];
    long nNodes = nfeat / D_FEAT;
    size_t need = (size_t)nfeat * sizeof(__half) + (size_t)nNodes * sizeof(float);

    if (P <= 0) return;

    if (ws_size < need || (nfeat % D_FEAT) != 0) {
        int threads = 2 * P;
        int grid = (threads + 255) / 256;
        jaccard_edge_kernel<<<grid, 256, 0, stream>>>(ei, w, feat, out, P, E);
        return;
    }

    __half* hfeat = (__half*)d_ws;
    float*  nrm   = (float*)((char*)d_ws + (size_t)nfeat * sizeof(__half));

    // Pass A: one quad per node -> 16 nodes per wave -> 64 nodes per block
    long nWaves = (nNodes + 15) / 16;
    long tA = nWaves * 64;
    int gridA = (int)((tA + 255) / 256);
    norm_convert_kernel<<<gridA, 256, 0, stream>>>(feat, hfeat, nrm, (int)nNodes);

    int tB = 4 * P;
    jaccard_edge_f16u_kernel<<<(tB + 255) / 256, 256, 0, stream>>>(
        ei, w, feat, hfeat, nrm, out, P, E);
}